// Round 3
// baseline (65.038 us; speedup 1.0000x reference)
//
#include <hip/hip_runtime.h>
#include <math.h>

// Problem constants (from reference): N=4, E=64, L=512, D=256
#define PN 4
#define PE 64
#define PL 512
#define PD 256
#define GC 16                  // token chunks
#define TOK_PER_CHUNK (PL / GC)     // 32
#define EG 4                   // entities per block (load reuse factor)
#define NEG (PE / EG)          // 16 entity groups
#define D4 (PD / 4)            // 64 float4 along D

// ---------------- Kernel 1: per-chunk partial (sum, max) for 4 entities ----
// grid = N * NEG * GC = 1024 blocks, 256 threads (4 waves).
// Each block reads a 32-token x 256-D tile ONCE and applies 4 entity masks.
__global__ __launch_bounds__(256) void mmp_partial(
    const float* __restrict__ doc_state,      // N x L x D
    const float* __restrict__ nodes_mapping,  // N x E x L
    float* __restrict__ part)                 // N x E x GC x 2 x D (8 MB)
{
    const int bx = blockIdx.x;
    const int c  = bx & (GC - 1);        // token chunk 0..15
    const int eg = (bx >> 4) & (NEG - 1);// entity group 0..15
    const int n  = bx >> 8;              // doc 0..3

    const int tid  = threadIdx.x;        // 0..255
    const int w    = tid >> 6;           // wave 0..3
    const int lane = tid & 63;           // float4 slot along D

    __shared__ float  smask[EG][TOK_PER_CHUNK];        // 4 x 32 floats
    __shared__ float4 s_sum[4][EG][D4];                // 16 KB
    __shared__ float4 s_max[4][EG][D4];                // 16 KB

    // Stage masks: 4 entities x 32 tokens = 128 floats.
    if (tid < EG * TOK_PER_CHUNK) {
        const int j = tid >> 5;          // entity-in-group
        const int t = tid & 31;          // token-in-chunk
        smask[j][t] = nodes_mapping[(size_t)(n * PE + eg * EG + j) * PL
                                    + c * TOK_PER_CHUNK + t];
    }
    __syncthreads();

    // doc_state tile for this chunk, viewed as float4 [L][64]
    const float4* ds = (const float4*)(doc_state + (size_t)n * PL * PD);
    const float4* dsp = ds + (size_t)(c * TOK_PER_CHUNK + w * 8) * D4 + lane;

    float4 sum[EG], mx[EG];
    #pragma unroll
    for (int j = 0; j < EG; ++j) {
        sum[j] = make_float4(0.f, 0.f, 0.f, 0.f);
        mx[j]  = make_float4(-INFINITY, -INFINITY, -INFINITY, -INFINITY);
    }

    // 8 tokens per wave; each loaded value reused by 4 entity masks.
    #pragma unroll
    for (int i = 0; i < 8; ++i) {
        const float4 s = dsp[i * D4];                 // coalesced 16B/lane
        #pragma unroll
        for (int j = 0; j < EG; ++j) {
            const float m = smask[j][w * 8 + i];      // wave-uniform broadcast
            const float vx = m * s.x, vy = m * s.y, vz = m * s.z, vw = m * s.w;
            sum[j].x += vx; sum[j].y += vy; sum[j].z += vz; sum[j].w += vw;
            mx[j].x = fmaxf(mx[j].x, vx);
            mx[j].y = fmaxf(mx[j].y, vy);
            mx[j].z = fmaxf(mx[j].z, vz);
            mx[j].w = fmaxf(mx[j].w, vw);
        }
    }

    #pragma unroll
    for (int j = 0; j < EG; ++j) {
        s_sum[w][j][lane] = sum[j];
        s_max[w][j][lane] = mx[j];
    }
    __syncthreads();

    // 256 threads reduce 4 waves for (entity j = tid>>6, both kinds).
    {
        const int j = tid >> 6;
        float4 tm = s_max[0][j][lane];
        float4 ts = s_sum[0][j][lane];
        #pragma unroll
        for (int w2 = 1; w2 < 4; ++w2) {
            const float4 m2 = s_max[w2][j][lane];
            const float4 s2 = s_sum[w2][j][lane];
            tm.x = fmaxf(tm.x, m2.x); tm.y = fmaxf(tm.y, m2.y);
            tm.z = fmaxf(tm.z, m2.z); tm.w = fmaxf(tm.w, m2.w);
            ts.x += s2.x; ts.y += s2.y; ts.z += s2.z; ts.w += s2.w;
        }
        // part layout: [n][e][c][kind][d], kind 0 = max, 1 = sum
        float4* p = (float4*)part;
        const size_t e    = (size_t)(n * PE + eg * EG + j);
        const size_t base = ((e * GC + c) * 2) * D4;
        p[base + lane]      = tm;   // kind 0: max
        p[base + D4 + lane] = ts;   // kind 1: sum
    }
}

// ---------------- Kernel 2: combine 16 chunk-partials per (n,e) -----------
// grid = N*E = 256 blocks, 128 threads: kind = tid>>6, lane = tid&63.
__global__ __launch_bounds__(128) void mmp_combine(
    const float* __restrict__ part,       // N x E x GC x 2 x D
    const float* __restrict__ nodes_len,  // N x E
    float* __restrict__ out)              // N x E x 2D
{
    const int ne   = blockIdx.x;          // 0..255
    const int tid  = threadIdx.x;
    const int k    = tid >> 6;            // 0 = max, 1 = sum->mean
    const int lane = tid & 63;

    const float4* p = (const float4*)part;
    const size_t base = (((size_t)ne * GC) * 2 + k) * D4 + lane;

    float4 acc = p[base];
    if (k == 0) {
        #pragma unroll
        for (int c = 1; c < GC; ++c) {
            const float4 v = p[base + (size_t)c * 2 * D4];
            acc.x = fmaxf(acc.x, v.x); acc.y = fmaxf(acc.y, v.y);
            acc.z = fmaxf(acc.z, v.z); acc.w = fmaxf(acc.w, v.w);
        }
    } else {
        #pragma unroll
        for (int c = 1; c < GC; ++c) {
            const float4 v = p[base + (size_t)c * 2 * D4];
            acc.x += v.x; acc.y += v.y; acc.z += v.z; acc.w += v.w;
        }
        const float len  = nodes_len[ne];
        const float slen = (len > 0.f) ? len : 1.0f;
        acc.x /= slen; acc.y /= slen; acc.z /= slen; acc.w /= slen;
    }

    // out per (n,e): 512 floats = [max(256) | mean(256)]
    float4* o = (float4*)out;
    o[(size_t)ne * 2 * D4 + k * D4 + lane] = acc;
}

extern "C" void kernel_launch(void* const* d_in, const int* in_sizes, int n_in,
                              void* d_out, int out_size, void* d_ws, size_t ws_size,
                              hipStream_t stream) {
    const float* doc_state     = (const float*)d_in[0];  // N*L*D
    const float* nodes_mapping = (const float*)d_in[1];  // N*E*L
    const float* nodes_len     = (const float*)d_in[2];  // N*E
    float* out  = (float*)d_out;                         // N*E*2D
    float* part = (float*)d_ws;                          // 8 MB partials

    mmp_partial<<<dim3(PN * NEG * GC), dim3(256), 0, stream>>>(
        doc_state, nodes_mapping, part);
    mmp_combine<<<dim3(PN * PE), dim3(128), 0, stream>>>(
        part, nodes_len, out);
}

// Round 4
// 63.181 us; speedup vs baseline: 1.0294x; 1.0294x over previous
//
#include <hip/hip_runtime.h>
#include <math.h>

// Problem constants (from reference): N=4, E=64, L=512, D=256
#define PN 4
#define PE 64
#define PL 512
#define PD 256
#define NWAVES 16          // 1024 threads = 16 waves/CU (4 per SIMD)
#define TOK_PER_WAVE (PL / NWAVES)   // 32 tokens per wave

// One block per (n,e). Port-bound: each block streams its 512 KB doc slice
// through the per-CU load port once (~64 B/cyc -> ~3.4 us floor, measured ~3.5).
__global__ __launch_bounds__(64 * NWAVES) void MeanMaxPooling_84473416778475_kernel(
    const float* __restrict__ doc_state,      // N x L x D
    const float* __restrict__ nodes_mapping,  // N x E x L
    const float* __restrict__ nodes_len,      // N x E
    float* __restrict__ out)                  // N x E x 2D
{
    const int ne   = blockIdx.x;     // 0..N*E-1
    const int n    = ne >> 6;        // / 64
    const int e    = ne & 63;        // % 64
    const int tid  = threadIdx.x;    // 0..1023
    const int w    = tid >> 6;       // wave 0..15
    const int lane = tid & 63;       // float4 index along D (64 * 4 = 256)

    __shared__ float  smask[PL];            // 2 KB
    __shared__ float4 s_sum[NWAVES][64];    // 16 KB
    __shared__ float4 s_max[NWAVES][64];    // 16 KB

    // Stage this (n,e)'s token mask: 512 floats.
    if (tid < PL) {
        smask[tid] = nodes_mapping[(size_t)(n * PE + e) * PL + tid];
    }
    __syncthreads();

    // doc_state for doc n, viewed as float4 [L][64]
    const float4* ds = (const float4*)(doc_state + (size_t)n * PL * PD);

    float4 sum = make_float4(0.f, 0.f, 0.f, 0.f);
    float4 mx  = make_float4(-INFINITY, -INFINITY, -INFINITY, -INFINITY);

    const int l0 = w * TOK_PER_WAVE;   // 32 contiguous tokens per wave
    #pragma unroll 8
    for (int i = 0; i < TOK_PER_WAVE; ++i) {
        const int l = l0 + i;
        const float  m = smask[l];           // wave-uniform broadcast (free)
        const float4 s = ds[l * 64 + lane];  // coalesced 16B/lane, L2-resident
        // v = mask * state; zeros from unselected tokens DO participate in max
        const float vx = m * s.x, vy = m * s.y, vz = m * s.z, vw = m * s.w;
        sum.x += vx; sum.y += vy; sum.z += vz; sum.w += vw;
        mx.x = fmaxf(mx.x, vx);
        mx.y = fmaxf(mx.y, vy);
        mx.z = fmaxf(mx.z, vz);
        mx.w = fmaxf(mx.w, vw);
    }

    s_sum[w][lane] = sum;
    s_max[w][lane] = mx;
    __syncthreads();

    // Wave 0 reduces the 16 per-wave partials and writes the output.
    if (tid < 64) {
        float4 tsum = s_sum[0][lane];
        float4 tmax = s_max[0][lane];
        #pragma unroll
        for (int j = 1; j < NWAVES; ++j) {
            const float4 s2 = s_sum[j][lane];
            const float4 m2 = s_max[j][lane];
            tsum.x += s2.x; tsum.y += s2.y; tsum.z += s2.z; tsum.w += s2.w;
            tmax.x = fmaxf(tmax.x, m2.x);
            tmax.y = fmaxf(tmax.y, m2.y);
            tmax.z = fmaxf(tmax.z, m2.z);
            tmax.w = fmaxf(tmax.w, m2.w);
        }
        const float len  = nodes_len[n * PE + e];
        const float slen = (len > 0.f) ? len : 1.0f;
        float4 mean;
        mean.x = tsum.x / slen;
        mean.y = tsum.y / slen;
        mean.z = tsum.z / slen;
        mean.w = tsum.w / slen;

        float4* o = (float4*)(out + (size_t)(n * PE + e) * 2 * PD);
        o[lane]      = tmax;   // max_pooled -> first D
        o[64 + lane] = mean;   // mean_pooled -> second D
    }
}

extern "C" void kernel_launch(void* const* d_in, const int* in_sizes, int n_in,
                              void* d_out, int out_size, void* d_ws, size_t ws_size,
                              hipStream_t stream) {
    const float* doc_state     = (const float*)d_in[0];  // N*L*D
    const float* nodes_mapping = (const float*)d_in[1];  // N*E*L
    const float* nodes_len     = (const float*)d_in[2];  // N*E
    float* out = (float*)d_out;                          // N*E*2D

    dim3 grid(PN * PE);        // 256 blocks, ~1 per CU
    dim3 block(64 * NWAVES);   // 1024 threads = 16 waves
    MeanMaxPooling_84473416778475_kernel<<<grid, block, 0, stream>>>(
        doc_state, nodes_mapping, nodes_len, out);
}